// Round 6
// baseline (2967.911 us; speedup 1.0000x reference)
//
#include <hip/hip_runtime.h>
#include <stdint.h>

#define S_LEN 2048
#define BATCH 32
#define DEMB  512
#define DRNN  256
#define G3    768   // 3*DRNN

typedef __bf16    bf16x8 __attribute__((ext_vector_type(8)));
typedef float     f32x4  __attribute__((ext_vector_type(4)));
typedef _Float16  f16x2  __attribute__((ext_vector_type(2)));
typedef _Float16  f16x8  __attribute__((ext_vector_type(8)));

__device__ __forceinline__ unsigned short f2b(float f) {    // f32 -> bf16 RNE
    unsigned int u = __builtin_bit_cast(unsigned int, f);
    unsigned int r = (u + 0x7fffu + ((u >> 16) & 1u)) >> 16;
    return (unsigned short)r;
}
__device__ __forceinline__ float sigm(float x) {
    float e = __builtin_amdgcn_exp2f(-1.4426950408889634f * x);
    return __builtin_amdgcn_rcpf(1.0f + e);
}
__device__ __forceinline__ float tanh_f(float x) {
    float e = __builtin_amdgcn_exp2f(2.8853900817779268f * x);  // e^(2x)
    return 1.0f - 2.0f * __builtin_amdgcn_rcpf(e + 1.0f);       // safe at +-inf
}
__device__ __forceinline__ float dot2acc(f16x2 w, f16x2 h, float acc) {
    return __builtin_amdgcn_fdot2(w, h, acc, false);
}
__device__ __forceinline__ f16x2 pk_f16(float lo, float hi) {
    return __builtin_bit_cast(f16x2, __builtin_amdgcn_cvt_pkrtz(lo, hi));
}

// ---------------- Kernel A: gi = x @ w_ih^T + b_ih  (both dirs, one chunk) --
__global__ __launch_bounds__(256) void gi_gemm(
    const float* __restrict__ x,
    const float* __restrict__ wih_f,
    const float* __restrict__ bih_f,
    const float* __restrict__ wih_b,
    const float* __restrict__ bih_b,
    float* __restrict__ gi,
    int p0, int chunkM)
{
    const int dir = blockIdx.z;
    const float* wih = dir ? wih_b : wih_f;
    const float* bih = dir ? bih_b : bih_f;
    float* giD = gi + (size_t)dir * (size_t)chunkM * G3;

    __shared__ __align__(16) unsigned short sA[128 * 32];
    __shared__ __align__(16) unsigned short sB[128 * 32];

    const int tid  = threadIdx.x;
    const int lane = tid & 63, wv = tid >> 6;
    const int wr = wv >> 1, wc = wv & 1;        // wave quadrant (2x2 of 64x64)
    const int lr = lane & 15, kq = lane >> 4;

    const int m0 = blockIdx.x * 128;
    const int n0 = blockIdx.y * 128;

    f32x4 acc[4][4];
    #pragma unroll
    for (int i = 0; i < 4; ++i)
        #pragma unroll
        for (int j = 0; j < 4; ++j) acc[i][j] = (f32x4){0.f, 0.f, 0.f, 0.f};

    const int srow = tid >> 3;            // 32 rows per pass, 8 threads/row
    const int scol = (tid & 7) * 4;       // 4 floats per thread

    for (int ks = 0; ks < 16; ++ks) {
        const int k0 = ks * 32;
        #pragma unroll
        for (int r = 0; r < 4; ++r) {
            const int row = srow + r * 32;
            {
                const int m = m0 + row;
                const int p = p0 + (m >> 5), b = m & 31;
                const int t = dir ? (S_LEN - 1 - p) : p;
                const float4 v = *(const float4*)&x[((size_t)t * BATCH + b) * DEMB + k0 + scol];
                ushort4 h4; h4.x = f2b(v.x); h4.y = f2b(v.y); h4.z = f2b(v.z); h4.w = f2b(v.w);
                *(ushort4*)&sA[row * 32 + scol] = h4;
            }
            {
                const float4 v = *(const float4*)&wih[(size_t)(n0 + row) * DEMB + k0 + scol];
                ushort4 h4; h4.x = f2b(v.x); h4.y = f2b(v.y); h4.z = f2b(v.z); h4.w = f2b(v.w);
                *(ushort4*)&sB[row * 32 + scol] = h4;
            }
        }
        __syncthreads();
        bf16x8 af[4], bfr[4];
        #pragma unroll
        for (int i = 0; i < 4; ++i) {
            af[i]  = *(const bf16x8*)&sA[(wr * 64 + i * 16 + lr) * 32 + kq * 8];
            bfr[i] = *(const bf16x8*)&sB[(wc * 64 + i * 16 + lr) * 32 + kq * 8];
        }
        #pragma unroll
        for (int i = 0; i < 4; ++i)
            #pragma unroll
            for (int j = 0; j < 4; ++j)
                acc[i][j] = __builtin_amdgcn_mfma_f32_16x16x32_bf16(
                    af[i], bfr[j], acc[i][j], 0, 0, 0);
        __syncthreads();
    }
    #pragma unroll
    for (int j = 0; j < 4; ++j) {
        const int g = n0 + wc * 64 + j * 16 + lr;
        const float bias = bih[g];
        #pragma unroll
        for (int i = 0; i < 4; ++i) {
            const int mbase = m0 + wr * 64 + i * 16 + kq * 4;
            #pragma unroll
            for (int r2 = 0; r2 < 4; ++r2)
                giD[(size_t)(mbase + r2) * G3 + g] = acc[i][j][r2] + bias;
        }
    }
}

// ---------------- Kernel B: the recurrence (one chunk) ----------------------
// 64 WGs: one (batch, direction) chain each. 1024 threads, 16 waves.
// Thread = (wave w, lane l): j = w*16 + (l&15) in [0,256), kq = l>>4 in [0,4)
// -> each thread owns a K-QUARTER (64 elems) of gate rows {j, 256+j, 512+j}.
// r,z gate weights in VGPRs (64 regs total -> fits 128-cap, no AGPR shuttle).
// n-gate weights in LDS [w][cc][l] (lane-contiguous ds_read_b128, offsets <=7KB).
// k-reduce = shfl_xor(16)+shfl_xor(32). h double-buffered + quarter-padded.
__global__ __launch_bounds__(1024, 4) void gru_rec(
    const float* __restrict__ gi,               // [2][chunk*32][768]
    const float* __restrict__ whh_f,
    const float* __restrict__ bhh_f,
    const float* __restrict__ whh_b,
    const float* __restrict__ bhh_b,
    float* __restrict__ out,                    // [S*B*512] ++ [2*B*256]
    float* __restrict__ hcarry,                 // [2*B*256]
    int p0, int chunk)
{
    const int wg  = blockIdx.x;
    const int b   = wg & 31, dir = wg >> 5;
    const float* whh = dir ? whh_b : whh_f;
    const float* bhh = dir ? bhh_b : bhh_f;
    const float* giD = gi + (size_t)dir * (size_t)(chunk * BATCH) * G3;

    const int tid = threadIdx.x;
    const int th  = tid >> 6, tl = tid & 63;
    const int j   = th * 16 + (tl & 15);
    const int kq  = tl >> 4;

    // n-gate: [th][cc][tl] f16x8 -> 8*1024*16 B = 128 KB
    __shared__ __align__(16) _Float16 w2L[8 * 1024 * 8];
    // h double buffer, 4 quarters of 64 + 8 pad f16 each (de-conflicts kq groups)
    __shared__ __align__(16) _Float16 h16[2][4 * 72];

    union u8 { f16x8 v; f16x2 p[4]; };

    // ---- r,z gate weights into registers (f32 -> packed f16), 64 VGPRs ----
    f16x8 w0[8], w1[8];
    {
        const float* s0 = whh + (size_t)(0   + j) * DRNN + kq * 64;
        const float* s1 = whh + (size_t)(256 + j) * DRNN + kq * 64;
        #pragma unroll
        for (int c = 0; c < 8; ++c) {
            float4 lo = *(const float4*)(s0 + c * 8);
            float4 hi = *(const float4*)(s0 + c * 8 + 4);
            u8 t;
            t.p[0] = pk_f16(lo.x, lo.y); t.p[1] = pk_f16(lo.z, lo.w);
            t.p[2] = pk_f16(hi.x, hi.y); t.p[3] = pk_f16(hi.z, hi.w);
            w0[c] = t.v;
            lo = *(const float4*)(s1 + c * 8);
            hi = *(const float4*)(s1 + c * 8 + 4);
            t.p[0] = pk_f16(lo.x, lo.y); t.p[1] = pk_f16(lo.z, lo.w);
            t.p[2] = pk_f16(hi.x, hi.y); t.p[3] = pk_f16(hi.z, hi.w);
            w1[c] = t.v;
            if (c & 1) __builtin_amdgcn_sched_barrier(0);   // cap load-hoist VGPR spike
        }
    }
    // ---- n-gate weights into LDS ----
    {
        f16x8* w2v = (f16x8*)w2L;
        const float* s2 = whh + (size_t)(512 + j) * DRNN + kq * 64;
        #pragma unroll
        for (int c = 0; c < 8; ++c) {
            float4 lo = *(const float4*)(s2 + c * 8);
            float4 hi = *(const float4*)(s2 + c * 8 + 4);
            u8 t;
            t.p[0] = pk_f16(lo.x, lo.y); t.p[1] = pk_f16(lo.z, lo.w);
            t.p[2] = pk_f16(hi.x, hi.y); t.p[3] = pk_f16(hi.z, hi.w);
            w2v[(th * 8 + c) * 64 + tl] = t.v;
            if (c & 1) __builtin_amdgcn_sched_barrier(0);
        }
    }

    const float bh0 = bhh[j], bh1 = bhh[256 + j], bh2 = bhh[512 + j];
    float hold = (p0 == 0) ? 0.f : hcarry[(dir * BATCH + b) * DRNN + j];
    if (kq == 0) h16[0][(j >> 6) * 72 + (j & 63)] = (_Float16)hold;
    __syncthreads();

    // prefetch gi for step 0 (kq-redundant, same addr -> broadcast)
    float c0, c1, c2;
    {
        const float* p = giD + (size_t)b * G3;
        c0 = p[j]; c1 = p[256 + j]; c2 = p[512 + j];
    }

    const f16x8* hvA = (const f16x8*)&h16[0][kq * 72];   // read, even steps
    const f16x8* hvB = (const f16x8*)&h16[1][kq * 72];   // read, odd steps
    _Float16* hwA = &h16[1][(j >> 6) * 72 + (j & 63)];   // write, even steps
    _Float16* hwB = &h16[0][(j >> 6) * 72 + (j & 63)];   // write, odd steps
    const f16x8* w2p = (const f16x8*)w2L + (size_t)th * 512 + tl;

    for (int step = 0; step < chunk; ++step) {
        const int pos = p0 + step;
        const int t = dir ? (S_LEN - 1 - pos) : pos;
        const bool odd = (step & 1) != 0;
        const f16x8* hv = odd ? hvB : hvA;
        _Float16*   hw = odd ? hwB : hwA;

        // prefetch next step's gi (hidden under the dot phase)
        float n0g = 0.f, n1g = 0.f, n2g = 0.f;
        if (step + 1 < chunk) {
            const float* p = giD + (size_t)((step + 1) * BATCH + b) * G3;
            n0g = p[j]; n1g = p[256 + j]; n2g = p[512 + j];
        }

        // ---- dot phase over this thread's K-quarter ----
        float a0 = 0.f, a1 = 0.f, a2 = 0.f;
        #pragma unroll
        for (int cc = 0; cc < 8; ++cc) {
            u8 H, A, B, C;
            H.v = hv[cc];             // 4 distinct addrs/wave, conflict-free (pad)
            A.v = w0[cc];
            B.v = w1[cc];
            C.v = w2p[cc * 64];       // lane-contiguous, offset cc*1024 B
            #pragma unroll
            for (int i = 0; i < 4; ++i) {
                a0 = dot2acc(A.p[i], H.p[i], a0);
                a1 = dot2acc(B.p[i], H.p[i], a1);
                a2 = dot2acc(C.p[i], H.p[i], a2);
            }
        }
        // ---- k-quarter reduce (in-wave, lanes {l, l^16, l^32, l^48}) ----
        a0 += __shfl_xor(a0, 16, 64); a0 += __shfl_xor(a0, 32, 64);
        a1 += __shfl_xor(a1, 16, 64); a1 += __shfl_xor(a1, 32, 64);
        a2 += __shfl_xor(a2, 16, 64); a2 += __shfl_xor(a2, 32, 64);

        // ---- gates (all lanes; kq quad computes identically) ----
        float r  = sigm(c0 + a0 + bh0);
        float z  = sigm(c1 + a1 + bh1);
        float n  = tanh_f(c2 + r * (a2 + bh2));
        float hy = n + z * (hold - n);
        hold = hy;
        if (kq == 0) {
            out[((size_t)t * BATCH + b) * 512 + dir * 256 + j] = hy;
            *hw = (_Float16)hy;       // write OTHER buffer -> no WAR race
        }
        __syncthreads();
        c0 = n0g; c1 = n1g; c2 = n2g;
    }

    if (kq == 0) {
        hcarry[(dir * BATCH + b) * DRNN + j] = hold;
        if (p0 + chunk == S_LEN)
            out[(size_t)S_LEN * BATCH * 512 + (dir * BATCH + b) * DRNN + j] = hold;
    }
}

// ---------------------------------------------------------------------------
extern "C" void kernel_launch(void* const* d_in, const int* in_sizes, int n_in,
                              void* d_out, int out_size, void* d_ws, size_t ws_size,
                              hipStream_t stream) {
    const float* x     = (const float*)d_in[0];
    const float* wih_f = (const float*)d_in[1];
    const float* whh_f = (const float*)d_in[2];
    const float* bih_f = (const float*)d_in[3];
    const float* bhh_f = (const float*)d_in[4];
    const float* wih_b = (const float*)d_in[5];
    const float* whh_b = (const float*)d_in[6];
    const float* bih_b = (const float*)d_in[7];
    const float* bhh_b = (const float*)d_in[8];
    float* out = (float*)d_out;

    const size_t carry_bytes = (size_t)2 * BATCH * DRNN * 4;    // 64 KB
    int chunk = 0;
    for (int c = S_LEN; c >= 16; c >>= 1) {
        size_t need = carry_bytes + (size_t)2 * c * BATCH * G3 * 4;
        if (ws_size >= need) { chunk = c; break; }
    }
    if (!chunk) return;   // ws too small — visible as unchanged output

    float* hcarry = (float*)d_ws;
    float* gi     = (float*)((char*)d_ws + carry_bytes);
    const int chunkM = chunk * BATCH;

    for (int p0 = 0; p0 < S_LEN; p0 += chunk) {
        gi_gemm<<<dim3(chunkM / 128, 6, 2), 256, 0, stream>>>(
            x, wih_f, bih_f, wih_b, bih_b, gi, p0, chunkM);
        gru_rec<<<dim3(64), 1024, 0, stream>>>(
            gi, whh_f, bhh_f, whh_b, bhh_b, out, hcarry, p0, chunk);
    }
}

// Round 7
// 2550.640 us; speedup vs baseline: 1.1636x; 1.1636x over previous
//
#include <hip/hip_runtime.h>
#include <stdint.h>

#define S_LEN 2048
#define BATCH 32
#define DEMB  512
#define DRNN  256
#define G3    768   // 3*DRNN

typedef __bf16    bf16x8 __attribute__((ext_vector_type(8)));
typedef float     f32x4  __attribute__((ext_vector_type(4)));
typedef _Float16  f16x2  __attribute__((ext_vector_type(2)));
typedef _Float16  f16x8  __attribute__((ext_vector_type(8)));

__device__ __forceinline__ unsigned short f2b(float f) {    // f32 -> bf16 RNE
    unsigned int u = __builtin_bit_cast(unsigned int, f);
    unsigned int r = (u + 0x7fffu + ((u >> 16) & 1u)) >> 16;
    return (unsigned short)r;
}
__device__ __forceinline__ float sigm(float x) {
    float e = __builtin_amdgcn_exp2f(-1.4426950408889634f * x);
    return __builtin_amdgcn_rcpf(1.0f + e);
}
__device__ __forceinline__ float tanh_f(float x) {
    float e = __builtin_amdgcn_exp2f(2.8853900817779268f * x);  // e^(2x)
    return 1.0f - 2.0f * __builtin_amdgcn_rcpf(e + 1.0f);       // safe at +-inf
}
__device__ __forceinline__ float dot2acc(f16x2 w, f16x2 h, float acc) {
    return __builtin_amdgcn_fdot2(w, h, acc, false);
}
__device__ __forceinline__ f16x2 pk_f16(float lo, float hi) {
    return __builtin_bit_cast(f16x2, __builtin_amdgcn_cvt_pkrtz(lo, hi));
}

// ---------------- Kernel A: gi = x @ w_ih^T + b_ih  (both dirs, one chunk) --
__global__ __launch_bounds__(256) void gi_gemm(
    const float* __restrict__ x,
    const float* __restrict__ wih_f,
    const float* __restrict__ bih_f,
    const float* __restrict__ wih_b,
    const float* __restrict__ bih_b,
    float* __restrict__ gi,
    int p0, int chunkM)
{
    const int dir = blockIdx.z;
    const float* wih = dir ? wih_b : wih_f;
    const float* bih = dir ? bih_b : bih_f;
    float* giD = gi + (size_t)dir * (size_t)chunkM * G3;

    __shared__ __align__(16) unsigned short sA[128 * 32];
    __shared__ __align__(16) unsigned short sB[128 * 32];

    const int tid  = threadIdx.x;
    const int lane = tid & 63, wv = tid >> 6;
    const int wr = wv >> 1, wc = wv & 1;        // wave quadrant (2x2 of 64x64)
    const int lr = lane & 15, kq = lane >> 4;

    const int m0 = blockIdx.x * 128;
    const int n0 = blockIdx.y * 128;

    f32x4 acc[4][4];
    #pragma unroll
    for (int i = 0; i < 4; ++i)
        #pragma unroll
        for (int j = 0; j < 4; ++j) acc[i][j] = (f32x4){0.f, 0.f, 0.f, 0.f};

    const int srow = tid >> 3;            // 32 rows per pass, 8 threads/row
    const int scol = (tid & 7) * 4;       // 4 floats per thread

    for (int ks = 0; ks < 16; ++ks) {
        const int k0 = ks * 32;
        #pragma unroll
        for (int r = 0; r < 4; ++r) {
            const int row = srow + r * 32;
            {
                const int m = m0 + row;
                const int p = p0 + (m >> 5), b = m & 31;
                const int t = dir ? (S_LEN - 1 - p) : p;
                const float4 v = *(const float4*)&x[((size_t)t * BATCH + b) * DEMB + k0 + scol];
                ushort4 h4; h4.x = f2b(v.x); h4.y = f2b(v.y); h4.z = f2b(v.z); h4.w = f2b(v.w);
                *(ushort4*)&sA[row * 32 + scol] = h4;
            }
            {
                const float4 v = *(const float4*)&wih[(size_t)(n0 + row) * DEMB + k0 + scol];
                ushort4 h4; h4.x = f2b(v.x); h4.y = f2b(v.y); h4.z = f2b(v.z); h4.w = f2b(v.w);
                *(ushort4*)&sB[row * 32 + scol] = h4;
            }
        }
        __syncthreads();
        bf16x8 af[4], bfr[4];
        #pragma unroll
        for (int i = 0; i < 4; ++i) {
            af[i]  = *(const bf16x8*)&sA[(wr * 64 + i * 16 + lr) * 32 + kq * 8];
            bfr[i] = *(const bf16x8*)&sB[(wc * 64 + i * 16 + lr) * 32 + kq * 8];
        }
        #pragma unroll
        for (int i = 0; i < 4; ++i)
            #pragma unroll
            for (int j = 0; j < 4; ++j)
                acc[i][j] = __builtin_amdgcn_mfma_f32_16x16x32_bf16(
                    af[i], bfr[j], acc[i][j], 0, 0, 0);
        __syncthreads();
    }
    #pragma unroll
    for (int j = 0; j < 4; ++j) {
        const int g = n0 + wc * 64 + j * 16 + lr;
        const float bias = bih[g];
        #pragma unroll
        for (int i = 0; i < 4; ++i) {
            const int mbase = m0 + wr * 64 + i * 16 + kq * 4;
            #pragma unroll
            for (int r2 = 0; r2 < 4; ++r2)
                giD[(size_t)(mbase + r2) * G3 + g] = acc[i][j][r2] + bias;
        }
    }
}

// ---------------- Kernel B: the recurrence (one chunk) ----------------------
// 64 WGs: one (batch, direction) chain each. 512 threads, 8 waves.
// Thread = (wave w, lane l): j = w*32 + (l&31) in [0,256), kh = l>>5 (k-half).
// ALL THREE gate weight slices in arch VGPRs (192 regs as 48 f16x8).
// amdgpu_waves_per_eu(2,2) pins the allocator's occupancy target to 2/EU
// (256-VGPR budget) so weights are NOT demoted to AGPR (the r3/r5/r6 bug:
// VGPR_Count 128/128/64 -> v_accvgpr_read shuttle on the serial path).
// LDS holds only the double-buffered h. One barrier per step. out-store
// AFTER the barrier so the pre-barrier vmcnt(0) drain overlaps next dot.
__global__ __launch_bounds__(512)
__attribute__((amdgpu_waves_per_eu(2, 2)))
void gru_rec(
    const float* __restrict__ gi,               // [2][chunk*32][768]
    const float* __restrict__ whh_f,
    const float* __restrict__ bhh_f,
    const float* __restrict__ whh_b,
    const float* __restrict__ bhh_b,
    float* __restrict__ out,                    // [S*B*512] ++ [2*B*256]
    float* __restrict__ hcarry,                 // [2*B*256]
    int p0, int chunk)
{
    const int wg  = blockIdx.x;
    const int b   = wg & 31, dir = wg >> 5;
    const float* whh = dir ? whh_b : whh_f;
    const float* bhh = dir ? bhh_b : bhh_f;
    const float* giD = gi + (size_t)dir * (size_t)(chunk * BATCH) * G3;

    const int tid = threadIdx.x;
    const int j   = ((tid >> 6) << 5) | (tid & 31);   // wave*32 + (lane&31)
    const int kh  = (tid >> 5) & 1;                   // k-half

    __shared__ __align__(16) _Float16 h16[2][DRNN];   // double buffer only

    union u8 { f16x8 v; f16x2 p[4]; };

    // ---- all 3 gate weight slices into registers (f32 -> packed f16) ----
    f16x8 w[3][16];                                   // 192 VGPRs
    #pragma unroll
    for (int g = 0; g < 3; ++g) {
        const float* s = whh + (size_t)(g * 256 + j) * DRNN + kh * 128;
        #pragma unroll
        for (int c = 0; c < 16; ++c) {
            float4 lo = *(const float4*)(s + c * 8);
            float4 hi = *(const float4*)(s + c * 8 + 4);
            u8 t;
            t.p[0] = pk_f16(lo.x, lo.y); t.p[1] = pk_f16(lo.z, lo.w);
            t.p[2] = pk_f16(hi.x, hi.y); t.p[3] = pk_f16(hi.z, hi.w);
            w[g][c] = t.v;
            if ((c & 3) == 3) __builtin_amdgcn_sched_barrier(0);  // cap hoist spike
        }
    }
    // pin weight registers to arch VGPRs
    #pragma unroll
    for (int g = 0; g < 3; ++g)
        #pragma unroll
        for (int c = 0; c < 16; ++c)
            asm volatile("" : "+v"(w[g][c]));

    const float bh0 = bhh[j], bh1 = bhh[256 + j], bh2 = bhh[512 + j];
    float hold = (p0 == 0) ? 0.f : hcarry[(dir * BATCH + b) * DRNN + j];
    if (kh == 0) h16[0][j] = (_Float16)hold;
    __syncthreads();

    // prefetch gi for step 0 (kh-redundant, same addr -> broadcast)
    float c0, c1, c2;
    {
        const float* p = giD + (size_t)b * G3;
        c0 = p[j]; c1 = p[256 + j]; c2 = p[512 + j];
    }

    const f16x8* hvA = (const f16x8*)&h16[0][kh * 128];   // read, even steps
    const f16x8* hvB = (const f16x8*)&h16[1][kh * 128];   // read, odd steps

    for (int step = 0; step < chunk; ++step) {
        const int pos = p0 + step;
        const int t = dir ? (S_LEN - 1 - pos) : pos;
        const bool odd = (step & 1) != 0;
        const f16x8* hv = odd ? hvB : hvA;

        // prefetch next step's gi (hidden under the dot phase)
        float n0g = 0.f, n1g = 0.f, n2g = 0.f;
        if (step + 1 < chunk) {
            const float* p = giD + (size_t)((step + 1) * BATCH + b) * G3;
            n0g = p[j]; n1g = p[256 + j]; n2g = p[512 + j];
        }

        // ---- dot phase over this thread's k-half (192 dot2, all from VGPR) --
        float a0 = 0.f, a1 = 0.f, a2 = 0.f;
        #pragma unroll
        for (int cc = 0; cc < 16; ++cc) {
            u8 H, A, B, C;
            H.v = hv[cc];             // uniform addr per half-wave -> broadcast
            A.v = w[0][cc]; B.v = w[1][cc]; C.v = w[2][cc];
            #pragma unroll
            for (int i = 0; i < 4; ++i) {
                a0 = dot2acc(A.p[i], H.p[i], a0);
                a1 = dot2acc(B.p[i], H.p[i], a1);
                a2 = dot2acc(C.p[i], H.p[i], a2);
            }
        }
        // ---- k-half reduce (lanes l and l^32 share the same j) ----
        a0 += __shfl_xor(a0, 32, 64);
        a1 += __shfl_xor(a1, 32, 64);
        a2 += __shfl_xor(a2, 32, 64);

        // ---- gates (all lanes; kh pair computes identically) ----
        float r  = sigm(c0 + a0 + bh0);
        float z  = sigm(c1 + a1 + bh1);
        float n  = tanh_f(c2 + r * (a2 + bh2));
        float hy = n + z * (hold - n);
        hold = hy;
        if (kh == 0) h16[odd ? 0 : 1][j] = (_Float16)hy;  // other buffer, no WAR
        __syncthreads();
        // store AFTER the barrier: the vmcnt(0)+lgkmcnt(0) drain before the
        // NEXT barrier gives this store a whole dot-phase to retire.
        if (kh == 0)
            out[((size_t)t * BATCH + b) * 512 + dir * 256 + j] = hy;
        c0 = n0g; c1 = n1g; c2 = n2g;
    }

    if (kh == 0) {
        hcarry[(dir * BATCH + b) * DRNN + j] = hold;
        if (p0 + chunk == S_LEN)
            out[(size_t)S_LEN * BATCH * 512 + (dir * BATCH + b) * DRNN + j] = hold;
    }
}

// ---------------------------------------------------------------------------
extern "C" void kernel_launch(void* const* d_in, const int* in_sizes, int n_in,
                              void* d_out, int out_size, void* d_ws, size_t ws_size,
                              hipStream_t stream) {
    const float* x     = (const float*)d_in[0];
    const float* wih_f = (const float*)d_in[1];
    const float* whh_f = (const float*)d_in[2];
    const float* bih_f = (const float*)d_in[3];
    const float* bhh_f = (const float*)d_in[4];
    const float* wih_b = (const float*)d_in[5];
    const float* whh_b = (const float*)d_in[6];
    const float* bih_b = (const float*)d_in[7];
    const float* bhh_b = (const float*)d_in[8];
    float* out = (float*)d_out;

    const size_t carry_bytes = (size_t)2 * BATCH * DRNN * 4;    // 64 KB
    int chunk = 0;
    for (int c = S_LEN; c >= 16; c >>= 1) {
        size_t need = carry_bytes + (size_t)2 * c * BATCH * G3 * 4;
        if (ws_size >= need) { chunk = c; break; }
    }
    if (!chunk) return;   // ws too small — visible as unchanged output

    float* hcarry = (float*)d_ws;
    float* gi     = (float*)((char*)d_ws + carry_bytes);
    const int chunkM = chunk * BATCH;

    for (int p0 = 0; p0 < S_LEN; p0 += chunk) {
        gi_gemm<<<dim3(chunkM / 128, 6, 2), 256, 0, stream>>>(
            x, wih_f, bih_f, wih_b, bih_b, gi, p0, chunkM);
        gru_rec<<<dim3(64), 512, 0, stream>>>(
            gi, whh_f, bhh_f, whh_b, bhh_b, out, hcarry, p0, chunk);
    }
}